// Round 2
// baseline (1264.568 us; speedup 1.0000x reference)
//
#include <hip/hip_runtime.h>
#include <math.h>

#define LOG2PI_F 1.8378770664093453f

// ws layout (floats)
#define WS_Q    0                       // 512
#define WS_SCAL 512                     // 32: [0]=step1 [1]=step2 [2]=logdet_LI [3..11]=w1_inv [12..20]=w2_inv
#define WS_M    544                     // 512*512 (L + I, consumed by blocked chol)
#define WS_CHR  (544 + 512*512)         // 500*64*3 = 96000
#define WS_S34  (WS_CHR + 96000)        // 16000

__device__ inline void inv3(const float* w, float* out){
  float a=w[0],b=w[1],c=w[2],d=w[3],e=w[4],f=w[5],g=w[6],h=w[7],i=w[8];
  float A = e*i - f*h;
  float B = -(d*i - f*g);
  float C = d*h - e*g;
  float det = a*A + b*B + c*C;
  float id = 1.0f/det;
  out[0]=A*id;            out[1]=-(b*i - c*h)*id; out[2]=(b*f - c*e)*id;
  out[3]=B*id;            out[4]=(a*i - c*g)*id;  out[5]=-(a*f - c*d)*id;
  out[6]=C*id;            out[7]=-(a*h - b*g)*id; out[8]=(a*e - b*d)*id;
}

// ---------------- prep: q, step1, step2, 3x3 inverses ----------------
__global__ __launch_bounds__(512) void k_prep(const float* __restrict__ mus,
    const float* __restrict__ fkw1, const float* __restrict__ fkb1,
    const float* __restrict__ fkw2, const float* __restrict__ fkb2,
    const float* __restrict__ dfw1, const float* __restrict__ dfw2,
    float* ws){
  int t = threadIdx.x;          // 0..511 == N
  __shared__ float red[512];
  float m0 = mus[t*3+0], m1 = mus[t*3+1], m2 = mus[t*3+2];
  float h0 = tanhf(fkw1[0]*m0 + fkw1[1]*m1 + fkw1[2]*m2 + fkb1[0]);
  float h1 = tanhf(fkw1[3]*m0 + fkw1[4]*m1 + fkw1[5]*m2 + fkb1[1]);
  float h2 = tanhf(fkw1[6]*m0 + fkw1[7]*m1 + fkw1[8]*m2 + fkb1[2]);
  float logq = fkw2[0]*h0 + fkw2[1]*h1 + fkw2[2]*h2 + fkb2[0];
  ws[WS_Q + t] = expf(logq);
  red[t] = -0.5f*(m0*m0 + m1*m1 + m2*m2);
  __syncthreads();
  for (int s = 256; s; s >>= 1){ if (t < s) red[t] += red[t+s]; __syncthreads(); }
  if (t == 0){
    ws[WS_SCAL+1] = red[0] - 512.0f*1.5f*LOG2PI_F;                       // step2
    ws[WS_SCAL+0] = 512.0f*logf(500.0f) - 500.0f - lgammaf(513.0f);      // step1
    ws[WS_SCAL+2] = 0.0f;                                                // logdet accumulator
    inv3(dfw1, ws + WS_SCAL + 3);
    inv3(dfw2, ws + WS_SCAL + 12);
  }
}

// ---------------- chromes: inverse flow on colors ----------------
__global__ __launch_bounds__(256) void k_chromes(const float* __restrict__ colors,
    const float* __restrict__ dfb1, const float* __restrict__ dfb2, float* ws){
  int id = blockIdx.x*256 + threadIdx.x;          // < 32000 exact
  const float* w1i = ws + WS_SCAL + 3;
  const float* w2i = ws + WS_SCAL + 12;
  float c0 = colors[id*3+0] - dfb2[0];
  float c1 = colors[id*3+1] - dfb2[1];
  float c2 = colors[id*3+2] - dfb2[2];
  float z0 = w2i[0]*c0 + w2i[1]*c1 + w2i[2]*c2;
  float z1 = w2i[3]*c0 + w2i[4]*c1 + w2i[5]*c2;
  float z2 = w2i[6]*c0 + w2i[7]*c1 + w2i[8]*c2;
  const float lo = -1.0f + 1e-6f, hi = 1.0f - 1e-6f;
  z0 = atanhf(fminf(fmaxf(z0, lo), hi)) - dfb1[0];
  z1 = atanhf(fminf(fmaxf(z1, lo), hi)) - dfb1[1];
  z2 = atanhf(fminf(fmaxf(z2, lo), hi)) - dfb1[2];
  ws[WS_CHR + id*3+0] = w1i[0]*z0 + w1i[1]*z1 + w1i[2]*z2;
  ws[WS_CHR + id*3+1] = w1i[3]*z0 + w1i[4]*z1 + w1i[5]*z2;
  ws[WS_CHR + id*3+2] = w1i[6]*z0 + w1i[7]*z1 + w1i[8]*z2;
}

// ---------------- build M = L + I ----------------
__global__ __launch_bounds__(256) void k_L(const float* __restrict__ mus, float* ws){
  int id = blockIdx.x*256 + threadIdx.x;          // < 262144 exact
  int i = id >> 9, j = id & 511;
  float dx = mus[i*3+0]-mus[j*3+0];
  float dy = mus[i*3+1]-mus[j*3+1];
  float dz = mus[i*3+2]-mus[j*3+2];
  float d2 = dx*dx + dy*dy + dz*dz;
  float v = ws[WS_Q+i]*ws[WS_Q+j]*expf(-0.5f*d2);
  if (i == j) v += 1.0f;
  ws[WS_M + id] = v;
}

// ---------------- blocked Cholesky: panel = 64x64 diag chol + trsm ----------------
// one block, 512 threads. Wave 0 does the diag chol (row-per-lane, shfl-only).
__global__ __launch_bounds__(512) void k_panel(float* ws, int k0){
  float* M = ws + WS_M;
  __shared__ float FT[64][64];   // FT[c][r] = L[r][c]; diag slot holds 1/Lcc, zeros above
  const int t = threadIdx.x;

  if (t < 64){
    float x[64];
    #pragma unroll
    for (int c = 0; c < 64; ++c) x[c] = M[(k0+t)*512 + k0 + c];
    float invd = 1.f, mydiag = 1.f;
    #pragma unroll
    for (int c = 0; c < 64; ++c){
      float piv = __shfl(x[c], c);
      float sq = sqrtf(fmaxf(piv, 1e-30f));
      float inv = 1.0f / sq;
      float xc = x[c] * inv;
      if (t == c){ xc = sq; invd = inv; mydiag = sq; }
      x[c] = xc;
      #pragma unroll
      for (int j = c + 1; j < 64; ++j){
        float vj = __shfl(xc, j);        // lane j's scaled column-c entry
        x[j] -= xc * vj;
      }
    }
    float lg = logf(mydiag);
    #pragma unroll
    for (int off = 32; off; off >>= 1) lg += __shfl_down(lg, off);
    if (t == 0) atomicAdd(&ws[WS_SCAL + 2], 2.f * lg);
    #pragma unroll
    for (int c = 0; c < 64; ++c)
      FT[c][t] = (t > c) ? x[c] : ((t == c) ? invd : 0.f);
  }
  __syncthreads();

  // trsm: rows k0+64 .. 511, one row per thread, row in registers
  const int H = 448 - k0;
  if (t < H){
    const int r = k0 + 64 + t;
    float y[64];
    #pragma unroll
    for (int c4 = 0; c4 < 16; ++c4){
      float4 v = *(const float4*)&M[r*512 + k0 + c4*4];
      y[c4*4+0]=v.x; y[c4*4+1]=v.y; y[c4*4+2]=v.z; y[c4*4+3]=v.w;
    }
    #pragma unroll
    for (int c = 0; c < 64; ++c){
      const float yc = y[c] * FT[c][c];      // FT[c][c] = 1/Lcc
      y[c] = yc;
      const int j0 = c + 1;
      const int ja = (j0 + 3) & ~3;
      const int jh = (ja < 64) ? ja : 64;
      #pragma unroll
      for (int j = j0; j < jh; ++j) y[j] -= yc * FT[c][j];
      #pragma unroll
      for (int j = ja; j < 64; j += 4){
        float4 f = *(const float4*)&FT[c][j];
        y[j+0] -= yc * f.x;
        y[j+1] -= yc * f.y;
        y[j+2] -= yc * f.z;
        y[j+3] -= yc * f.w;
      }
    }
    #pragma unroll
    for (int c4 = 0; c4 < 16; ++c4){
      float4 v;
      v.x=y[c4*4+0]; v.y=y[c4*4+1]; v.z=y[c4*4+2]; v.w=y[c4*4+3];
      *(float4*)&M[r*512 + k0 + c4*4] = v;
    }
  }
}

// ---------------- blocked Cholesky: trailing SYRK, one 64x64 tile per block ----------------
__global__ __launch_bounds__(256) void k_syrk(float* ws, int k0){
  float* M = ws + WS_M;
  __shared__ float AT[64][64];   // AT[k][r]: panel rows of the A tile, transposed
  __shared__ float BT[64][64];
  const int t = threadIdx.x;
  int tp = blockIdx.x;
  int a = 0;
  while ((a + 1) * (a + 2) / 2 <= tp) a++;
  const int bb = tp - a * (a + 1) / 2;
  const int Ra = k0 + 64 + a * 64;
  const int Cb = k0 + 64 + bb * 64;

  {
    const int row = t & 63;
    const int cb  = (t >> 6) * 16;       // 4 thread-groups x 16 cols
    #pragma unroll
    for (int q = 0; q < 4; ++q){
      const int c = cb + q*4;
      float4 v = *(const float4*)&M[(Ra + row)*512 + k0 + c];
      AT[c+0][row]=v.x; AT[c+1][row]=v.y; AT[c+2][row]=v.z; AT[c+3][row]=v.w;
      float4 w = *(const float4*)&M[(Cb + row)*512 + k0 + c];
      BT[c+0][row]=w.x; BT[c+1][row]=w.y; BT[c+2][row]=w.z; BT[c+3][row]=w.w;
    }
  }
  __syncthreads();

  const int ti = t >> 4, tj = t & 15;
  float acc[4][4];
  #pragma unroll
  for (int i = 0; i < 4; ++i)
    #pragma unroll
    for (int j = 0; j < 4; ++j) acc[i][j] = 0.f;
  #pragma unroll 8
  for (int k = 0; k < 64; ++k){
    float4 av = *(const float4*)&AT[k][ti*4];
    float4 bv = *(const float4*)&BT[k][tj*4];
    acc[0][0]+=av.x*bv.x; acc[0][1]+=av.x*bv.y; acc[0][2]+=av.x*bv.z; acc[0][3]+=av.x*bv.w;
    acc[1][0]+=av.y*bv.x; acc[1][1]+=av.y*bv.y; acc[1][2]+=av.y*bv.z; acc[1][3]+=av.y*bv.w;
    acc[2][0]+=av.z*bv.x; acc[2][1]+=av.z*bv.y; acc[2][2]+=av.z*bv.z; acc[2][3]+=av.z*bv.w;
    acc[3][0]+=av.w*bv.x; acc[3][1]+=av.w*bv.y; acc[3][2]+=av.w*bv.z; acc[3][3]+=av.w*bv.w;
  }
  #pragma unroll
  for (int i = 0; i < 4; ++i){
    const int r = Ra + ti*4 + i;
    float4 v = *(float4*)&M[r*512 + Cb + tj*4];
    v.x -= acc[i][0]; v.y -= acc[i][1]; v.z -= acc[i][2]; v.w -= acc[i][3];
    *(float4*)&M[r*512 + Cb + tj*4] = v;
  }
}

// ---------------- 16000 small 64x64 logdets + step4, one wave per block ----------------
__global__ __launch_bounds__(64) void k_small(const int* __restrict__ align,
    const float* __restrict__ mus, float* ws){
  const int b = blockIdx.x;              // l = b>>5, a = b&31
  const int t = threadIdx.x;             // 0..63
  __shared__ float4 pt[64];
  __shared__ float col[64];
  const int idx = align[b*64 + t];
  float4 own;
  own.x = mus[idx*3+0]; own.y = mus[idx*3+1]; own.z = mus[idx*3+2];
  own.w = ws[WS_Q + idx];
  pt[t] = own;
  __syncthreads();
  float x[64];
  #pragma unroll
  for (int j = 0; j < 64; ++j){
    float4 o = pt[j];
    float dx = own.x - o.x, dy = own.y - o.y, dz = own.z - o.z;
    float d2 = dx*dx + dy*dy + dz*dz;
    float v = own.w * o.w * expf(-0.5f*d2);
    if (j == t) v += 1e-6f;
    x[j] = v;
  }
  float mydiag = 1.f;
  #pragma unroll
  for (int c = 0; c < 64; ++c){
    float piv = __shfl(x[c], c);
    float sq = sqrtf(fmaxf(piv, 1e-30f));
    float inv = 1.0f / sq;
    float xc = x[c] * inv;
    if (t == c){ xc = sq; mydiag = sq; }
    x[c] = xc;
    col[t] = (t > c) ? xc : 0.f;
    __syncthreads();
    const int j0 = c + 1;
    const int ja = (j0 + 3) & ~3;
    const int jh = (ja < 64) ? ja : 64;
    #pragma unroll
    for (int j = j0; j < jh; ++j) x[j] -= xc * col[j];
    #pragma unroll
    for (int j = ja; j < 64; j += 4){
      float4 cv = *(const float4*)&col[j];
      x[j+0] -= xc * cv.x;
      x[j+1] -= xc * cv.y;
      x[j+2] -= xc * cv.z;
      x[j+3] -= xc * cv.w;
    }
    __syncthreads();
  }
  const float* ch = ws + WS_CHR + ((b >> 5)*64 + t)*3;
  float d0 = ch[0] - own.x, d1 = ch[1] - own.y, d2 = ch[2] - own.z;
  float v = 2.f*logf(mydiag) - 0.5f*(d0*d0 + d1*d1 + d2*d2);
  #pragma unroll
  for (int off = 32; off; off >>= 1) v += __shfl_down(v, off);
  if (t == 0) ws[WS_S34 + b] = v - 96.f*LOG2PI_F;
}

// ---------------- final: lse over A, sum over langs, assemble scalar ----------------
__global__ __launch_bounds__(512) void k_final(const float* __restrict__ ws, float* __restrict__ out){
  __shared__ float red[512];
  int t = threadIdx.x;
  float v = 0.f;
  if (t < 500){
    const float* s = ws + WS_S34 + t*32;
    float mx = -1e30f;
    for (int a = 0; a < 32; ++a) mx = fmaxf(mx, s[a]);
    float sum = 0.f;
    for (int a = 0; a < 32; ++a) sum += expf(s[a] - mx);
    v = mx + logf(sum);
  }
  red[t] = v;
  __syncthreads();
  for (int s = 256; s; s >>= 1){ if (t < s) red[t] += red[t+s]; __syncthreads(); }
  if (t == 0){
    float step1 = ws[WS_SCAL+0];
    float step2 = ws[WS_SCAL+1];
    float ld    = ws[WS_SCAL+2];
    float step34 = red[0] - 500.f*ld;
    out[0] = -(step1 + step2 + step34);
  }
}

extern "C" void kernel_launch(void* const* d_in, const int* in_sizes, int n_in,
                              void* d_out, int out_size, void* d_ws, size_t ws_size,
                              hipStream_t stream) {
  const float* colors = (const float*)d_in[0];
  const int*   align  = (const int*)  d_in[1];
  const float* mus    = (const float*)d_in[2];
  const float* fkw1   = (const float*)d_in[3];
  const float* fkb1   = (const float*)d_in[4];
  const float* fkw2   = (const float*)d_in[5];
  const float* fkb2   = (const float*)d_in[6];
  const float* dfw1   = (const float*)d_in[7];
  const float* dfb1   = (const float*)d_in[8];
  const float* dfw2   = (const float*)d_in[9];
  const float* dfb2   = (const float*)d_in[10];
  float* ws  = (float*)d_ws;
  float* out = (float*)d_out;

  hipLaunchKernelGGL(k_prep,    dim3(1),     dim3(512), 0, stream,
                     mus, fkw1, fkb1, fkw2, fkb2, dfw1, dfw2, ws);
  hipLaunchKernelGGL(k_chromes, dim3(125),   dim3(256), 0, stream, colors, dfb1, dfb2, ws);
  hipLaunchKernelGGL(k_L,       dim3(1024),  dim3(256), 0, stream, mus, ws);
  hipLaunchKernelGGL(k_small,   dim3(16000), dim3(64),  0, stream, align, mus, ws);
  for (int p = 0; p < 8; ++p){
    const int k0 = p * 64;
    hipLaunchKernelGGL(k_panel, dim3(1), dim3(512), 0, stream, ws, k0);
    const int m = 7 - p;
    if (m > 0){
      hipLaunchKernelGGL(k_syrk, dim3(m*(m+1)/2), dim3(256), 0, stream, ws, k0);
    }
  }
  hipLaunchKernelGGL(k_final,   dim3(1),     dim3(512), 0, stream, ws, out);
}

// Round 3
// 1238.070 us; speedup vs baseline: 1.0214x; 1.0214x over previous
//
#include <hip/hip_runtime.h>
#include <math.h>

#define LOG2PI_F 1.8378770664093453f

// ws layout (floats)
#define WS_Q    0                       // 512
#define WS_SCAL 512                     // 32: [0]=step1 [1]=step2 [2]=logdet_LI [3..11]=w1_inv [12..20]=w2_inv
#define WS_M    544                     // 512*512 (L + I, consumed by blocked chol)
#define WS_CHR  (544 + 512*512)         // 500*64*3 = 96000
#define WS_S34  (WS_CHR + 96000)        // 16000

__device__ inline void inv3(const float* w, float* out){
  float a=w[0],b=w[1],c=w[2],d=w[3],e=w[4],f=w[5],g=w[6],h=w[7],i=w[8];
  float A = e*i - f*h;
  float B = -(d*i - f*g);
  float C = d*h - e*g;
  float det = a*A + b*B + c*C;
  float id = 1.0f/det;
  out[0]=A*id;            out[1]=-(b*i - c*h)*id; out[2]=(b*f - c*e)*id;
  out[3]=B*id;            out[4]=(a*i - c*g)*id;  out[5]=-(a*f - c*d)*id;
  out[6]=C*id;            out[7]=-(a*h - b*g)*id; out[8]=(a*e - b*d)*id;
}

// ---------------- prep: q, step1, step2, 3x3 inverses ----------------
__global__ __launch_bounds__(512) void k_prep(const float* __restrict__ mus,
    const float* __restrict__ fkw1, const float* __restrict__ fkb1,
    const float* __restrict__ fkw2, const float* __restrict__ fkb2,
    const float* __restrict__ dfw1, const float* __restrict__ dfw2,
    float* ws){
  int t = threadIdx.x;          // 0..511 == N
  __shared__ float red[512];
  float m0 = mus[t*3+0], m1 = mus[t*3+1], m2 = mus[t*3+2];
  float h0 = tanhf(fkw1[0]*m0 + fkw1[1]*m1 + fkw1[2]*m2 + fkb1[0]);
  float h1 = tanhf(fkw1[3]*m0 + fkw1[4]*m1 + fkw1[5]*m2 + fkb1[1]);
  float h2 = tanhf(fkw1[6]*m0 + fkw1[7]*m1 + fkw1[8]*m2 + fkb1[2]);
  float logq = fkw2[0]*h0 + fkw2[1]*h1 + fkw2[2]*h2 + fkb2[0];
  ws[WS_Q + t] = expf(logq);
  red[t] = -0.5f*(m0*m0 + m1*m1 + m2*m2);
  __syncthreads();
  for (int s = 256; s; s >>= 1){ if (t < s) red[t] += red[t+s]; __syncthreads(); }
  if (t == 0){
    ws[WS_SCAL+1] = red[0] - 512.0f*1.5f*LOG2PI_F;                       // step2
    ws[WS_SCAL+0] = 512.0f*logf(500.0f) - 500.0f - lgammaf(513.0f);      // step1
    ws[WS_SCAL+2] = 0.0f;                                                // logdet accumulator
    inv3(dfw1, ws + WS_SCAL + 3);
    inv3(dfw2, ws + WS_SCAL + 12);
  }
}

// ---------------- chromes: inverse flow on colors ----------------
__global__ __launch_bounds__(256) void k_chromes(const float* __restrict__ colors,
    const float* __restrict__ dfb1, const float* __restrict__ dfb2, float* ws){
  int id = blockIdx.x*256 + threadIdx.x;          // < 32000 exact
  const float* w1i = ws + WS_SCAL + 3;
  const float* w2i = ws + WS_SCAL + 12;
  float c0 = colors[id*3+0] - dfb2[0];
  float c1 = colors[id*3+1] - dfb2[1];
  float c2 = colors[id*3+2] - dfb2[2];
  float z0 = w2i[0]*c0 + w2i[1]*c1 + w2i[2]*c2;
  float z1 = w2i[3]*c0 + w2i[4]*c1 + w2i[5]*c2;
  float z2 = w2i[6]*c0 + w2i[7]*c1 + w2i[8]*c2;
  const float lo = -1.0f + 1e-6f, hi = 1.0f - 1e-6f;
  z0 = atanhf(fminf(fmaxf(z0, lo), hi)) - dfb1[0];
  z1 = atanhf(fminf(fmaxf(z1, lo), hi)) - dfb1[1];
  z2 = atanhf(fminf(fmaxf(z2, lo), hi)) - dfb1[2];
  ws[WS_CHR + id*3+0] = w1i[0]*z0 + w1i[1]*z1 + w1i[2]*z2;
  ws[WS_CHR + id*3+1] = w1i[3]*z0 + w1i[4]*z1 + w1i[5]*z2;
  ws[WS_CHR + id*3+2] = w1i[6]*z0 + w1i[7]*z1 + w1i[8]*z2;
}

// ---------------- build M = L + I ----------------
__global__ __launch_bounds__(256) void k_L(const float* __restrict__ mus, float* ws){
  int id = blockIdx.x*256 + threadIdx.x;          // < 262144 exact
  int i = id >> 9, j = id & 511;
  float dx = mus[i*3+0]-mus[j*3+0];
  float dy = mus[i*3+1]-mus[j*3+1];
  float dz = mus[i*3+2]-mus[j*3+2];
  float d2 = dx*dx + dy*dy + dz*dz;
  float v = ws[WS_Q+i]*ws[WS_Q+j]*expf(-0.5f*d2);
  if (i == j) v += 1.0f;
  ws[WS_M + id] = v;
}

// ---------------- blocked Cholesky panel, B=64: diag chol (wave0) + shfl trsm ----------------
// Factor is register-distributed for the trsm: lane j of every wave holds factor
// row j in fr[64]; inner update is shfl+fma only (no LDS in the hot loop).
__global__ __launch_bounds__(512) void k_panel(float* ws, int k0){
  float* M = ws + WS_M;
  __shared__ float Frow[64][68];   // row-major factor, +4 pad (16B-aligned rows, 8-way banks)
  __shared__ float dinv[64];
  const int t = threadIdx.x;

  if (t < 64){
    float x[64];
    #pragma unroll
    for (int c4 = 0; c4 < 16; ++c4){
      float4 v = *(const float4*)&M[(k0+t)*512 + k0 + c4*4];
      x[c4*4+0]=v.x; x[c4*4+1]=v.y; x[c4*4+2]=v.z; x[c4*4+3]=v.w;
    }
    float invd = 1.f, mydiag = 1.f;
    #pragma unroll
    for (int c = 0; c < 64; ++c){
      float piv = __shfl(x[c], c);
      float sq = sqrtf(fmaxf(piv, 1e-30f));
      float inv = 1.0f / sq;
      float xc = x[c] * inv;
      if (t == c){ xc = sq; invd = inv; mydiag = sq; }
      x[c] = xc;
      #pragma unroll
      for (int j = c + 1; j < 64; ++j){
        float vj = __shfl(xc, j);
        x[j] -= xc * vj;
      }
    }
    float lg = __logf(mydiag);
    #pragma unroll
    for (int off = 32; off; off >>= 1) lg += __shfl_down(lg, off);
    if (t == 0) atomicAdd(&ws[WS_SCAL + 2], 2.f * lg);
    dinv[t] = invd;
    // store row t of the factor (x[c]=L[t][c] for c<=t; entries above diag unused)
    #pragma unroll
    for (int c4 = 0; c4 < 16; ++c4){
      float4 v;
      v.x=x[c4*4+0]; v.y=x[c4*4+1]; v.z=x[c4*4+2]; v.w=x[c4*4+3];
      *(float4*)&Frow[t][c4*4] = v;
    }
  }
  __syncthreads();

  // trsm: rows k0+64 .. 511, one row per thread, factor via register-distribution + shfl
  const int Ht = 448 - k0;
  if (t < Ht){
    const int r = k0 + 64 + t;
    const int lane = t & 63;
    float fr[64];
    #pragma unroll
    for (int c4 = 0; c4 < 16; ++c4){
      float4 v = *(const float4*)&Frow[lane][c4*4];
      fr[c4*4+0]=v.x; fr[c4*4+1]=v.y; fr[c4*4+2]=v.z; fr[c4*4+3]=v.w;
    }
    const float di = dinv[lane];
    float y[64];
    #pragma unroll
    for (int c4 = 0; c4 < 16; ++c4){
      float4 v = *(const float4*)&M[r*512 + k0 + c4*4];
      y[c4*4+0]=v.x; y[c4*4+1]=v.y; y[c4*4+2]=v.z; y[c4*4+3]=v.w;
    }
    #pragma unroll
    for (int c = 0; c < 64; ++c){
      const float invc = __shfl(di, c);
      const float yc = y[c] * invc;
      y[c] = yc;
      #pragma unroll
      for (int j = c + 1; j < 64; ++j){
        float fj = __shfl(fr[c], j);     // lane j holds L[j][c]
        y[j] -= yc * fj;
      }
    }
    #pragma unroll
    for (int c4 = 0; c4 < 16; ++c4){
      float4 v;
      v.x=y[c4*4+0]; v.y=y[c4*4+1]; v.z=y[c4*4+2]; v.w=y[c4*4+3];
      *(float4*)&M[r*512 + k0 + c4*4] = v;
    }
  }
}

// ---------------- blocked Cholesky: trailing SYRK, one 64x64 tile per block ----------------
__global__ __launch_bounds__(256) void k_syrk(float* ws, int k0){
  float* M = ws + WS_M;
  __shared__ float AT[64][64];   // AT[k][r]: panel rows of the A tile, transposed
  __shared__ float BT[64][64];
  const int t = threadIdx.x;
  int tp = blockIdx.x;
  int a = 0;
  while ((a + 1) * (a + 2) / 2 <= tp) a++;
  const int bb = tp - a * (a + 1) / 2;
  const int Ra = k0 + 64 + a * 64;
  const int Cb = k0 + 64 + bb * 64;

  {
    const int row = t & 63;
    const int cb  = (t >> 6) * 16;       // 4 thread-groups x 16 cols
    #pragma unroll
    for (int q = 0; q < 4; ++q){
      const int c = cb + q*4;
      float4 v = *(const float4*)&M[(Ra + row)*512 + k0 + c];
      AT[c+0][row]=v.x; AT[c+1][row]=v.y; AT[c+2][row]=v.z; AT[c+3][row]=v.w;
      float4 w = *(const float4*)&M[(Cb + row)*512 + k0 + c];
      BT[c+0][row]=w.x; BT[c+1][row]=w.y; BT[c+2][row]=w.z; BT[c+3][row]=w.w;
    }
  }
  __syncthreads();

  const int ti = t >> 4, tj = t & 15;
  float acc[4][4];
  #pragma unroll
  for (int i = 0; i < 4; ++i)
    #pragma unroll
    for (int j = 0; j < 4; ++j) acc[i][j] = 0.f;
  #pragma unroll 8
  for (int k = 0; k < 64; ++k){
    float4 av = *(const float4*)&AT[k][ti*4];
    float4 bv = *(const float4*)&BT[k][tj*4];
    acc[0][0]+=av.x*bv.x; acc[0][1]+=av.x*bv.y; acc[0][2]+=av.x*bv.z; acc[0][3]+=av.x*bv.w;
    acc[1][0]+=av.y*bv.x; acc[1][1]+=av.y*bv.y; acc[1][2]+=av.y*bv.z; acc[1][3]+=av.y*bv.w;
    acc[2][0]+=av.z*bv.x; acc[2][1]+=av.z*bv.y; acc[2][2]+=av.z*bv.z; acc[2][3]+=av.z*bv.w;
    acc[3][0]+=av.w*bv.x; acc[3][1]+=av.w*bv.y; acc[3][2]+=av.w*bv.z; acc[3][3]+=av.w*bv.w;
  }
  #pragma unroll
  for (int i = 0; i < 4; ++i){
    const int r = Ra + ti*4 + i;
    float4 v = *(float4*)&M[r*512 + Cb + tj*4];
    v.x -= acc[i][0]; v.y -= acc[i][1]; v.z -= acc[i][2]; v.w -= acc[i][3];
    *(float4*)&M[r*512 + Cb + tj*4] = v;
  }
}

// ---------------- 16000 small 64x64 logdets + step4 ----------------
// One wave per matrix, 4 matrices per block. No LDS, no barriers: build the
// row via shfl, Cholesky column updates via shfl+fma, rsqrt pivots.
__global__ __launch_bounds__(256) void k_small(const int* __restrict__ align,
    const float* __restrict__ mus, float* ws){
  const int b = blockIdx.x*4 + (threadIdx.x >> 6);   // matrix id, < 16000
  const int t = threadIdx.x & 63;
  const int idx = align[b*64 + t];
  const float ox = mus[idx*3+0], oy = mus[idx*3+1], oz = mus[idx*3+2];
  const float ow = ws[WS_Q + idx];
  float x[64];
  #pragma unroll
  for (int j = 0; j < 64; ++j){
    float px = __shfl(ox, j), py = __shfl(oy, j), pz = __shfl(oz, j), pw = __shfl(ow, j);
    float dx = ox-px, dy = oy-py, dz = oz-pz;
    float v = ow * pw * __expf(-0.5f*(dx*dx + dy*dy + dz*dz));
    x[j] = (j == t) ? v + 1e-6f : v;
  }
  float mydiag = 1.f;
  #pragma unroll
  for (int c = 0; c < 64; ++c){
    float piv = fmaxf(__shfl(x[c], c), 1e-30f);
    float rs = rsqrtf(piv);
    float xc = x[c] * rs;
    float sq = piv * rs;
    if (t == c){ xc = sq; mydiag = sq; }
    x[c] = xc;
    #pragma unroll
    for (int j = c + 1; j < 64; ++j){
      float vj = __shfl(xc, j);
      x[j] -= xc * vj;
    }
  }
  const float* ch = ws + WS_CHR + ((b >> 5)*64 + t)*3;
  float d0 = ch[0] - ox, d1 = ch[1] - oy, d2 = ch[2] - oz;
  float v = 2.f*__logf(mydiag) - 0.5f*(d0*d0 + d1*d1 + d2*d2);
  #pragma unroll
  for (int off = 32; off; off >>= 1) v += __shfl_down(v, off);
  if (t == 0) ws[WS_S34 + b] = v - 96.f*LOG2PI_F;
}

// ---------------- final: lse over A, sum over langs, assemble scalar ----------------
__global__ __launch_bounds__(512) void k_final(const float* __restrict__ ws, float* __restrict__ out){
  __shared__ float red[512];
  int t = threadIdx.x;
  float v = 0.f;
  if (t < 500){
    const float* s = ws + WS_S34 + t*32;
    float mx = -1e30f;
    for (int a = 0; a < 32; ++a) mx = fmaxf(mx, s[a]);
    float sum = 0.f;
    for (int a = 0; a < 32; ++a) sum += expf(s[a] - mx);
    v = mx + logf(sum);
  }
  red[t] = v;
  __syncthreads();
  for (int s = 256; s; s >>= 1){ if (t < s) red[t] += red[t+s]; __syncthreads(); }
  if (t == 0){
    float step1 = ws[WS_SCAL+0];
    float step2 = ws[WS_SCAL+1];
    float ld    = ws[WS_SCAL+2];
    float step34 = red[0] - 500.f*ld;
    out[0] = -(step1 + step2 + step34);
  }
}

extern "C" void kernel_launch(void* const* d_in, const int* in_sizes, int n_in,
                              void* d_out, int out_size, void* d_ws, size_t ws_size,
                              hipStream_t stream) {
  const float* colors = (const float*)d_in[0];
  const int*   align  = (const int*)  d_in[1];
  const float* mus    = (const float*)d_in[2];
  const float* fkw1   = (const float*)d_in[3];
  const float* fkb1   = (const float*)d_in[4];
  const float* fkw2   = (const float*)d_in[5];
  const float* fkb2   = (const float*)d_in[6];
  const float* dfw1   = (const float*)d_in[7];
  const float* dfb1   = (const float*)d_in[8];
  const float* dfw2   = (const float*)d_in[9];
  const float* dfb2   = (const float*)d_in[10];
  float* ws  = (float*)d_ws;
  float* out = (float*)d_out;

  hipLaunchKernelGGL(k_prep,    dim3(1),     dim3(512), 0, stream,
                     mus, fkw1, fkb1, fkw2, fkb2, dfw1, dfw2, ws);
  hipLaunchKernelGGL(k_chromes, dim3(125),   dim3(256), 0, stream, colors, dfb1, dfb2, ws);
  hipLaunchKernelGGL(k_L,       dim3(1024),  dim3(256), 0, stream, mus, ws);
  for (int p = 0; p < 8; ++p){
    const int k0 = p * 64;
    hipLaunchKernelGGL(k_panel, dim3(1), dim3(512), 0, stream, ws, k0);
    const int m = 7 - p;
    if (m > 0){
      hipLaunchKernelGGL(k_syrk, dim3(m*(m+1)/2), dim3(256), 0, stream, ws, k0);
    }
  }
  hipLaunchKernelGGL(k_small,   dim3(4000),  dim3(256), 0, stream, align, mus, ws);
  hipLaunchKernelGGL(k_final,   dim3(1),     dim3(512), 0, stream, ws, out);
}

// Round 4
// 1101.416 us; speedup vs baseline: 1.1481x; 1.1241x over previous
//
#include <hip/hip_runtime.h>
#include <math.h>

#define LOG2PI_F 1.8378770664093453f

// ws layout (floats)
#define WS_Q    0                       // 512
#define WS_SCAL 512                     // 32: [0]=step1 [1]=step2 [2]=logdet_LI [3..11]=w1_inv [12..20]=w2_inv
#define WS_M    544                     // 512*512 (L + I, consumed by blocked chol)
#define WS_CHR  (544 + 512*512)         // 500*64*3 = 96000
#define WS_S34  (WS_CHR + 96000)        // 16000

__device__ inline void inv3(const float* w, float* out){
  float a=w[0],b=w[1],c=w[2],d=w[3],e=w[4],f=w[5],g=w[6],h=w[7],i=w[8];
  float A = e*i - f*h;
  float B = -(d*i - f*g);
  float C = d*h - e*g;
  float det = a*A + b*B + c*C;
  float id = 1.0f/det;
  out[0]=A*id;            out[1]=-(b*i - c*h)*id; out[2]=(b*f - c*e)*id;
  out[3]=B*id;            out[4]=(a*i - c*g)*id;  out[5]=-(a*f - c*d)*id;
  out[6]=C*id;            out[7]=-(a*h - b*g)*id; out[8]=(a*e - b*d)*id;
}

// ---------------- prep: q, step1, step2, 3x3 inverses ----------------
__global__ __launch_bounds__(512) void k_prep(const float* __restrict__ mus,
    const float* __restrict__ fkw1, const float* __restrict__ fkb1,
    const float* __restrict__ fkw2, const float* __restrict__ fkb2,
    const float* __restrict__ dfw1, const float* __restrict__ dfw2,
    float* ws){
  int t = threadIdx.x;          // 0..511 == N
  __shared__ float red[512];
  float m0 = mus[t*3+0], m1 = mus[t*3+1], m2 = mus[t*3+2];
  float h0 = tanhf(fkw1[0]*m0 + fkw1[1]*m1 + fkw1[2]*m2 + fkb1[0]);
  float h1 = tanhf(fkw1[3]*m0 + fkw1[4]*m1 + fkw1[5]*m2 + fkb1[1]);
  float h2 = tanhf(fkw1[6]*m0 + fkw1[7]*m1 + fkw1[8]*m2 + fkb1[2]);
  float logq = fkw2[0]*h0 + fkw2[1]*h1 + fkw2[2]*h2 + fkb2[0];
  ws[WS_Q + t] = expf(logq);
  red[t] = -0.5f*(m0*m0 + m1*m1 + m2*m2);
  __syncthreads();
  for (int s = 256; s; s >>= 1){ if (t < s) red[t] += red[t+s]; __syncthreads(); }
  if (t == 0){
    ws[WS_SCAL+1] = red[0] - 512.0f*1.5f*LOG2PI_F;                       // step2
    ws[WS_SCAL+0] = 512.0f*logf(500.0f) - 500.0f - lgammaf(513.0f);      // step1
    ws[WS_SCAL+2] = 0.0f;                                                // logdet accumulator
    inv3(dfw1, ws + WS_SCAL + 3);
    inv3(dfw2, ws + WS_SCAL + 12);
  }
}

// ---------------- chromes: inverse flow on colors ----------------
__global__ __launch_bounds__(256) void k_chromes(const float* __restrict__ colors,
    const float* __restrict__ dfb1, const float* __restrict__ dfb2, float* ws){
  int id = blockIdx.x*256 + threadIdx.x;          // < 32000 exact
  const float* w1i = ws + WS_SCAL + 3;
  const float* w2i = ws + WS_SCAL + 12;
  float c0 = colors[id*3+0] - dfb2[0];
  float c1 = colors[id*3+1] - dfb2[1];
  float c2 = colors[id*3+2] - dfb2[2];
  float z0 = w2i[0]*c0 + w2i[1]*c1 + w2i[2]*c2;
  float z1 = w2i[3]*c0 + w2i[4]*c1 + w2i[5]*c2;
  float z2 = w2i[6]*c0 + w2i[7]*c1 + w2i[8]*c2;
  const float lo = -1.0f + 1e-6f, hi = 1.0f - 1e-6f;
  z0 = atanhf(fminf(fmaxf(z0, lo), hi)) - dfb1[0];
  z1 = atanhf(fminf(fmaxf(z1, lo), hi)) - dfb1[1];
  z2 = atanhf(fminf(fmaxf(z2, lo), hi)) - dfb1[2];
  ws[WS_CHR + id*3+0] = w1i[0]*z0 + w1i[1]*z1 + w1i[2]*z2;
  ws[WS_CHR + id*3+1] = w1i[3]*z0 + w1i[4]*z1 + w1i[5]*z2;
  ws[WS_CHR + id*3+2] = w1i[6]*z0 + w1i[7]*z1 + w1i[8]*z2;
}

// ---------------- build M = L + I ----------------
__global__ __launch_bounds__(256) void k_L(const float* __restrict__ mus, float* ws){
  int id = blockIdx.x*256 + threadIdx.x;          // < 262144 exact
  int i = id >> 9, j = id & 511;
  float dx = mus[i*3+0]-mus[j*3+0];
  float dy = mus[i*3+1]-mus[j*3+1];
  float dz = mus[i*3+2]-mus[j*3+2];
  float d2 = dx*dx + dy*dy + dz*dz;
  float v = ws[WS_Q+i]*ws[WS_Q+j]*expf(-0.5f*d2);
  if (i == j) v += 1.0f;
  ws[WS_M + id] = v;
}

// ---------------- blocked Cholesky panel, B=64 ----------------
// Factor stored column-major in LDS with zeros at j<=c (diag separated into
// dinv). All hot-loop LDS reads are uniform-address float4 broadcasts; the
// zero padding makes the aligned float4 updates branch-free.
__global__ __launch_bounds__(512) void k_panel(float* ws, int k0){
  float* M = ws + WS_M;
  __shared__ float FC[64*64];    // FC[c*64+j] = L[j][c] for j>c, else 0
  __shared__ float dinv[64];     // 1/Lcc
  const int t = threadIdx.x;

  // preload trsm row while wave0 will do the diag chol
  const int Ht = 448 - k0;
  float y[64];
  if (t < Ht){
    const int r = k0 + 64 + t;
    #pragma unroll
    for (int c4 = 0; c4 < 16; ++c4){
      float4 v = *(const float4*)&M[r*512 + k0 + c4*4];
      y[c4*4+0]=v.x; y[c4*4+1]=v.y; y[c4*4+2]=v.z; y[c4*4+3]=v.w;
    }
  }

  if (t < 64){          // wave 0: 64x64 diag Cholesky, row per lane
    float x[64];
    #pragma unroll
    for (int c4 = 0; c4 < 16; ++c4){
      float4 v = *(const float4*)&M[(k0+t)*512 + k0 + c4*4];
      x[c4*4+0]=v.x; x[c4*4+1]=v.y; x[c4*4+2]=v.z; x[c4*4+3]=v.w;
    }
    float mydiag = 1.f;
    #pragma unroll
    for (int c = 0; c < 64; ++c){
      float piv = fmaxf(__shfl(x[c], c), 1e-30f);   // uniform lane -> readlane
      float rs = rsqrtf(piv);
      float xc = x[c] * rs;                         // lane c: xc = sqrt(piv)
      if (t == c){ mydiag = xc; dinv[c] = rs; }
      FC[c*64 + t] = (t > c) ? xc : 0.f;
      const int ja0 = (c+1) & ~3;
      #pragma unroll
      for (int j = ja0; j < 64; j += 4){
        float4 f = *(const float4*)&FC[c*64 + j];   // uniform broadcast; zeros kill j<=c
        x[j+0] -= xc * f.x;
        x[j+1] -= xc * f.y;
        x[j+2] -= xc * f.z;
        x[j+3] -= xc * f.w;
      }
    }
    float lg = __logf(mydiag);
    #pragma unroll
    for (int off = 32; off; off >>= 1) lg += __shfl_down(lg, off);
    if (t == 0) atomicAdd(&ws[WS_SCAL + 2], 2.f * lg);
  }
  __syncthreads();

  // trsm: rows k0+64..511, one per thread; pure uniform-broadcast fmas
  if (t < Ht){
    const int r = k0 + 64 + t;
    #pragma unroll
    for (int c = 0; c < 64; ++c){
      const float yc = y[c] * dinv[c];
      y[c] = yc;
      const int ja0 = (c+1) & ~3;
      #pragma unroll
      for (int j = ja0; j < 64; j += 4){
        float4 f = *(const float4*)&FC[c*64 + j];   // zeros at j<=c -> no-op
        y[j+0] -= yc * f.x;
        y[j+1] -= yc * f.y;
        y[j+2] -= yc * f.z;
        y[j+3] -= yc * f.w;
      }
    }
    #pragma unroll
    for (int c4 = 0; c4 < 16; ++c4){
      float4 v;
      v.x=y[c4*4+0]; v.y=y[c4*4+1]; v.z=y[c4*4+2]; v.w=y[c4*4+3];
      *(float4*)&M[r*512 + k0 + c4*4] = v;
    }
  }
}

// ---------------- blocked Cholesky: trailing SYRK, one 64x64 tile per block ----------------
__global__ __launch_bounds__(256) void k_syrk(float* ws, int k0){
  float* M = ws + WS_M;
  __shared__ float AT[64][64];   // AT[k][r]: panel rows of the A tile, transposed
  __shared__ float BT[64][64];
  const int t = threadIdx.x;
  int tp = blockIdx.x;
  int a = 0;
  while ((a + 1) * (a + 2) / 2 <= tp) a++;
  const int bb = tp - a * (a + 1) / 2;
  const int Ra = k0 + 64 + a * 64;
  const int Cb = k0 + 64 + bb * 64;

  {
    const int row = t & 63;
    const int cb  = (t >> 6) * 16;       // 4 thread-groups x 16 cols
    #pragma unroll
    for (int q = 0; q < 4; ++q){
      const int c = cb + q*4;
      float4 v = *(const float4*)&M[(Ra + row)*512 + k0 + c];
      AT[c+0][row]=v.x; AT[c+1][row]=v.y; AT[c+2][row]=v.z; AT[c+3][row]=v.w;
      float4 w = *(const float4*)&M[(Cb + row)*512 + k0 + c];
      BT[c+0][row]=w.x; BT[c+1][row]=w.y; BT[c+2][row]=w.z; BT[c+3][row]=w.w;
    }
  }
  __syncthreads();

  const int ti = t >> 4, tj = t & 15;
  float acc[4][4];
  #pragma unroll
  for (int i = 0; i < 4; ++i)
    #pragma unroll
    for (int j = 0; j < 4; ++j) acc[i][j] = 0.f;
  #pragma unroll 8
  for (int k = 0; k < 64; ++k){
    float4 av = *(const float4*)&AT[k][ti*4];
    float4 bv = *(const float4*)&BT[k][tj*4];
    acc[0][0]+=av.x*bv.x; acc[0][1]+=av.x*bv.y; acc[0][2]+=av.x*bv.z; acc[0][3]+=av.x*bv.w;
    acc[1][0]+=av.y*bv.x; acc[1][1]+=av.y*bv.y; acc[1][2]+=av.y*bv.z; acc[1][3]+=av.y*bv.w;
    acc[2][0]+=av.z*bv.x; acc[2][1]+=av.z*bv.y; acc[2][2]+=av.z*bv.z; acc[2][3]+=av.z*bv.w;
    acc[3][0]+=av.w*bv.x; acc[3][1]+=av.w*bv.y; acc[3][2]+=av.w*bv.z; acc[3][3]+=av.w*bv.w;
  }
  #pragma unroll
  for (int i = 0; i < 4; ++i){
    const int r = Ra + ti*4 + i;
    float4 v = *(float4*)&M[r*512 + Cb + tj*4];
    v.x -= acc[i][0]; v.y -= acc[i][1]; v.z -= acc[i][2]; v.w -= acc[i][3];
    *(float4*)&M[r*512 + Cb + tj*4] = v;
  }
}

// ---------------- 16000 small 64x64 logdets + step4 ----------------
// One wave per matrix, 4 waves (matrices) per block, each wave its own LDS
// slice -> wave-coherent, no barriers. Column broadcast = zero-padded scaled
// column written once, read back as uniform float4 broadcasts (branch-free).
__global__ __launch_bounds__(256) void k_small(const int* __restrict__ align,
    const float* __restrict__ mus, float* ws){
  const int wid = threadIdx.x >> 6;
  const int b = blockIdx.x*4 + wid;      // matrix id = l*32+a, < 16000
  const int t = threadIdx.x & 63;
  __shared__ float4 pt[4][64];
  __shared__ float col[4][64];
  const int idx = align[b*64 + t];
  float4 own;
  own.x = mus[idx*3+0]; own.y = mus[idx*3+1]; own.z = mus[idx*3+2];
  own.w = ws[WS_Q + idx];
  pt[wid][t] = own;
  // wave-coherent read-back (same wave wrote it; compiler orders via alias)
  float x[64];
  #pragma unroll
  for (int j = 0; j < 64; ++j){
    float4 o = pt[wid][j];                 // uniform b128 broadcast
    float dx = own.x - o.x, dy = own.y - o.y, dz = own.z - o.z;
    float v = own.w * o.w * __expf(-0.5f*(dx*dx + dy*dy + dz*dz));
    x[j] = (j == t) ? v + 1e-6f : v;
  }
  float mydiag = 1.f;
  #pragma unroll
  for (int c = 0; c < 64; ++c){
    float piv = fmaxf(__shfl(x[c], c), 1e-30f);   // uniform lane -> readlane
    float rs = rsqrtf(piv);
    float xc = x[c] * rs;                          // lane c: xc = sqrt(piv)
    if (t == c) mydiag = xc;
    col[wid][t] = (t > c) ? xc : 0.f;              // zero-padded scaled column
    const int ja0 = (c+1) & ~3;
    #pragma unroll
    for (int j = ja0; j < 64; j += 4){
      float4 cv = *(const float4*)&col[wid][j];    // uniform broadcast
      x[j+0] -= xc * cv.x;
      x[j+1] -= xc * cv.y;
      x[j+2] -= xc * cv.z;
      x[j+3] -= xc * cv.w;
    }
  }
  const float* ch = ws + WS_CHR + ((b >> 5)*64 + t)*3;
  float d0 = ch[0] - own.x, d1 = ch[1] - own.y, d2 = ch[2] - own.z;
  float v = 2.f*__logf(mydiag) - 0.5f*(d0*d0 + d1*d1 + d2*d2);
  #pragma unroll
  for (int off = 32; off; off >>= 1) v += __shfl_down(v, off);
  if (t == 0) ws[WS_S34 + b] = v - 96.f*LOG2PI_F;
}

// ---------------- final: lse over A, sum over langs, assemble scalar ----------------
__global__ __launch_bounds__(512) void k_final(const float* __restrict__ ws, float* __restrict__ out){
  __shared__ float red[512];
  int t = threadIdx.x;
  float v = 0.f;
  if (t < 500){
    const float* s = ws + WS_S34 + t*32;
    float mx = -1e30f;
    for (int a = 0; a < 32; ++a) mx = fmaxf(mx, s[a]);
    float sum = 0.f;
    for (int a = 0; a < 32; ++a) sum += expf(s[a] - mx);
    v = mx + logf(sum);
  }
  red[t] = v;
  __syncthreads();
  for (int s = 256; s; s >>= 1){ if (t < s) red[t] += red[t+s]; __syncthreads(); }
  if (t == 0){
    float step1 = ws[WS_SCAL+0];
    float step2 = ws[WS_SCAL+1];
    float ld    = ws[WS_SCAL+2];
    float step34 = red[0] - 500.f*ld;
    out[0] = -(step1 + step2 + step34);
  }
}

extern "C" void kernel_launch(void* const* d_in, const int* in_sizes, int n_in,
                              void* d_out, int out_size, void* d_ws, size_t ws_size,
                              hipStream_t stream) {
  const float* colors = (const float*)d_in[0];
  const int*   align  = (const int*)  d_in[1];
  const float* mus    = (const float*)d_in[2];
  const float* fkw1   = (const float*)d_in[3];
  const float* fkb1   = (const float*)d_in[4];
  const float* fkw2   = (const float*)d_in[5];
  const float* fkb2   = (const float*)d_in[6];
  const float* dfw1   = (const float*)d_in[7];
  const float* dfb1   = (const float*)d_in[8];
  const float* dfw2   = (const float*)d_in[9];
  const float* dfb2   = (const float*)d_in[10];
  float* ws  = (float*)d_ws;
  float* out = (float*)d_out;

  hipLaunchKernelGGL(k_prep,    dim3(1),     dim3(512), 0, stream,
                     mus, fkw1, fkb1, fkw2, fkb2, dfw1, dfw2, ws);
  hipLaunchKernelGGL(k_chromes, dim3(125),   dim3(256), 0, stream, colors, dfb1, dfb2, ws);
  hipLaunchKernelGGL(k_L,       dim3(1024),  dim3(256), 0, stream, mus, ws);
  for (int p = 0; p < 8; ++p){
    const int k0 = p * 64;
    hipLaunchKernelGGL(k_panel, dim3(1), dim3(512), 0, stream, ws, k0);
    const int m = 7 - p;
    if (m > 0){
      hipLaunchKernelGGL(k_syrk, dim3(m*(m+1)/2), dim3(256), 0, stream, ws, k0);
    }
  }
  hipLaunchKernelGGL(k_small,   dim3(4000),  dim3(256), 0, stream, align, mus, ws);
  hipLaunchKernelGGL(k_final,   dim3(1),     dim3(512), 0, stream, ws, out);
}

// Round 5
// 964.880 us; speedup vs baseline: 1.3106x; 1.1415x over previous
//
#include <hip/hip_runtime.h>
#include <math.h>

#define LOG2PI_F 1.8378770664093453f

// ws layout (floats)
#define WS_Q    0                       // 512
#define WS_SCAL 512                     // [0]=step1 [1]=step2 [2]=logdet_LI [3..11]=w1_inv [12..20]=w2_inv
#define WS_M    544                     // 512*512
#define WS_CHR  (544 + 512*512)         // 500*64*3
#define WS_S34  (WS_CHR + 96000)        // 16000
#define WS_FC   (WS_S34 + 16000)        // 4096: current panel factor, col-major zero-padded
#define WS_DINV (WS_FC + 4096)          // 64: 1/Lcc

__device__ inline void inv3(const float* w, float* out){
  float a=w[0],b=w[1],c=w[2],d=w[3],e=w[4],f=w[5],g=w[6],h=w[7],i=w[8];
  float A = e*i - f*h;
  float B = -(d*i - f*g);
  float C = d*h - e*g;
  float det = a*A + b*B + c*C;
  float id = 1.0f/det;
  out[0]=A*id;            out[1]=-(b*i - c*h)*id; out[2]=(b*f - c*e)*id;
  out[3]=B*id;            out[4]=(a*i - c*g)*id;  out[5]=-(a*f - c*d)*id;
  out[6]=C*id;            out[7]=-(a*h - b*g)*id; out[8]=(a*e - b*d)*id;
}

// ---------------- prep ----------------
__global__ __launch_bounds__(512) void k_prep(const float* __restrict__ mus,
    const float* __restrict__ fkw1, const float* __restrict__ fkb1,
    const float* __restrict__ fkw2, const float* __restrict__ fkb2,
    const float* __restrict__ dfw1, const float* __restrict__ dfw2,
    float* ws){
  int t = threadIdx.x;
  __shared__ float red[512];
  float m0 = mus[t*3+0], m1 = mus[t*3+1], m2 = mus[t*3+2];
  float h0 = tanhf(fkw1[0]*m0 + fkw1[1]*m1 + fkw1[2]*m2 + fkb1[0]);
  float h1 = tanhf(fkw1[3]*m0 + fkw1[4]*m1 + fkw1[5]*m2 + fkb1[1]);
  float h2 = tanhf(fkw1[6]*m0 + fkw1[7]*m1 + fkw1[8]*m2 + fkb1[2]);
  float logq = fkw2[0]*h0 + fkw2[1]*h1 + fkw2[2]*h2 + fkb2[0];
  ws[WS_Q + t] = expf(logq);
  red[t] = -0.5f*(m0*m0 + m1*m1 + m2*m2);
  __syncthreads();
  for (int s = 256; s; s >>= 1){ if (t < s) red[t] += red[t+s]; __syncthreads(); }
  if (t == 0){
    ws[WS_SCAL+1] = red[0] - 512.0f*1.5f*LOG2PI_F;
    ws[WS_SCAL+0] = 512.0f*logf(500.0f) - 500.0f - lgammaf(513.0f);
    ws[WS_SCAL+2] = 0.0f;
    inv3(dfw1, ws + WS_SCAL + 3);
    inv3(dfw2, ws + WS_SCAL + 12);
  }
}

// ---------------- fused: chromes (blocks 0..124) + build L+I (blocks 125..1148) ----------------
__global__ __launch_bounds__(256) void k_mid(const float* __restrict__ colors,
    const float* __restrict__ dfb1, const float* __restrict__ dfb2,
    const float* __restrict__ mus, float* ws){
  if (blockIdx.x < 125){
    int id = blockIdx.x*256 + threadIdx.x;          // < 32000
    const float* w1i = ws + WS_SCAL + 3;
    const float* w2i = ws + WS_SCAL + 12;
    float c0 = colors[id*3+0] - dfb2[0];
    float c1 = colors[id*3+1] - dfb2[1];
    float c2 = colors[id*3+2] - dfb2[2];
    float z0 = w2i[0]*c0 + w2i[1]*c1 + w2i[2]*c2;
    float z1 = w2i[3]*c0 + w2i[4]*c1 + w2i[5]*c2;
    float z2 = w2i[6]*c0 + w2i[7]*c1 + w2i[8]*c2;
    const float lo = -1.0f + 1e-6f, hi = 1.0f - 1e-6f;
    z0 = atanhf(fminf(fmaxf(z0, lo), hi)) - dfb1[0];
    z1 = atanhf(fminf(fmaxf(z1, lo), hi)) - dfb1[1];
    z2 = atanhf(fminf(fmaxf(z2, lo), hi)) - dfb1[2];
    ws[WS_CHR + id*3+0] = w1i[0]*z0 + w1i[1]*z1 + w1i[2]*z2;
    ws[WS_CHR + id*3+1] = w1i[3]*z0 + w1i[4]*z1 + w1i[5]*z2;
    ws[WS_CHR + id*3+2] = w1i[6]*z0 + w1i[7]*z1 + w1i[8]*z2;
  } else {
    int id = (blockIdx.x - 125)*256 + threadIdx.x;  // < 262144
    int i = id >> 9, j = id & 511;
    float dx = mus[i*3+0]-mus[j*3+0];
    float dy = mus[i*3+1]-mus[j*3+1];
    float dz = mus[i*3+2]-mus[j*3+2];
    float d2 = dx*dx + dy*dy + dz*dz;
    float v = ws[WS_Q+i]*ws[WS_Q+j]*expf(-0.5f*d2);
    if (i == j) v += 1.0f;
    ws[WS_M + id] = v;
  }
}

// ---------------- 64x64 chol by one wave; factor -> ws (zero-padded col-major) ----------------
// src: row base pointer (row t at src[t*stride]); colbuf: 64-float LDS scratch
// (wave-coherent, no barriers). Adds 2*sum(log diag) to ws[WS_SCAL+2].
__device__ __forceinline__ void chol64_wave(const float* src, int stride, float* ws, float* colbuf){
  const int t = threadIdx.x & 63;
  float x[64];
  #pragma unroll
  for (int c4 = 0; c4 < 16; ++c4){
    float4 v = *(const float4*)&src[t*stride + c4*4];
    x[c4*4+0]=v.x; x[c4*4+1]=v.y; x[c4*4+2]=v.z; x[c4*4+3]=v.w;
  }
  float mydiag = 1.f;
  #pragma unroll
  for (int c = 0; c < 64; ++c){
    float piv = fmaxf(__shfl(x[c], c), 1e-30f);
    float rs = rsqrtf(piv);
    float xc = x[c] * rs;                       // lane c: sqrt(piv)
    if (t == c) mydiag = xc;
    float cval = (t > c) ? xc : 0.f;
    colbuf[t] = cval;                           // same-wave LDS ordering
    x[c] = xc;
    ws[WS_FC + c*64 + t] = cval;                // factor column to global
    if (t == c) ws[WS_DINV + c] = rs;
    const int ja0 = (c+1) & ~3;
    #pragma unroll
    for (int j = ja0; j < 64; j += 4){
      float4 f = *(const float4*)&colbuf[j];    // zeros kill j<=c
      x[j+0] -= xc * f.x;
      x[j+1] -= xc * f.y;
      x[j+2] -= xc * f.z;
      x[j+3] -= xc * f.w;
    }
  }
  float lg = __logf(mydiag);
  #pragma unroll
  for (int off = 32; off; off >>= 1) lg += __shfl_down(lg, off);
  if (t == 0) atomicAdd(&ws[WS_SCAL + 2], 2.f * lg);
}

// ---------------- small-matrix role: one 64x64 logdet + step4 per wave ----------------
__device__ __forceinline__ void small_role(const int* __restrict__ align,
    const float* __restrict__ mus, float* ws, int b, float4* pt, float* col){
  const int t = threadIdx.x & 63;
  const int idx = align[b*64 + t];
  float4 own;
  own.x = mus[idx*3+0]; own.y = mus[idx*3+1]; own.z = mus[idx*3+2];
  own.w = ws[WS_Q + idx];
  pt[t] = own;
  float x[64];
  #pragma unroll
  for (int j = 0; j < 64; ++j){
    float4 o = pt[j];
    float dx = own.x - o.x, dy = own.y - o.y, dz = own.z - o.z;
    float v = own.w * o.w * __expf(-0.5f*(dx*dx + dy*dy + dz*dz));
    x[j] = (j == t) ? v + 1e-6f : v;
  }
  float mydiag = 1.f;
  #pragma unroll
  for (int c = 0; c < 64; ++c){
    float piv = fmaxf(__shfl(x[c], c), 1e-30f);
    float rs = rsqrtf(piv);
    float xc = x[c] * rs;
    if (t == c) mydiag = xc;
    col[t] = (t > c) ? xc : 0.f;
    const int ja0 = (c+1) & ~3;
    #pragma unroll
    for (int j = ja0; j < 64; j += 4){
      float4 cv = *(const float4*)&col[j];
      x[j+0] -= xc * cv.x;
      x[j+1] -= xc * cv.y;
      x[j+2] -= xc * cv.z;
      x[j+3] -= xc * cv.w;
    }
  }
  const float* ch = ws + WS_CHR + ((b >> 5)*64 + t)*3;
  float d0 = ch[0] - own.x, d1 = ch[1] - own.y, d2 = ch[2] - own.z;
  float v = 2.f*__logf(mydiag) - 0.5f*(d0*d0 + d1*d1 + d2*d2);
  #pragma unroll
  for (int off = 32; off; off >>= 1) v += __shfl_down(v, off);
  if (t == 0) ws[WS_S34 + b] = v - 96.f*LOG2PI_F;
}

// ---------------- diag chol of panel 0 (block 0) + k_small slice (other blocks) ----------------
__global__ __launch_bounds__(256) void k_d0s(const int* __restrict__ align,
    const float* __restrict__ mus, float* ws, int mb_base, int mb_end){
  __shared__ float smem[1280];
  if (blockIdx.x == 0){
    if (threadIdx.x < 64) chol64_wave(ws + WS_M, 512, ws, smem);
  } else {
    const int wid = threadIdx.x >> 6;
    const int b = mb_base + ((int)blockIdx.x - 1)*4 + wid;
    if (b < mb_end)
      small_role(align, mus, ws, b, ((float4*)smem) + wid*64, smem + 1024 + wid*64);
  }
}

// ---------------- trsm (blocks < tb; one row/thread, uniform global factor reads) + slice ----------------
__global__ __launch_bounds__(256) void k_trsmS(const int* __restrict__ align,
    const float* __restrict__ mus, float* ws, int k0, int tb, int mb_base, int mb_end){
  __shared__ float smem[1280];
  if ((int)blockIdx.x < tb){
    const int rel = (int)blockIdx.x*256 + threadIdx.x;
    const int rows = 448 - k0;
    if (rel < rows){
      const int r = k0 + 64 + rel;
      float* M = ws + WS_M;
      const float* fc   = ws + WS_FC;
      const float* dinv = ws + WS_DINV;
      float y[64];
      #pragma unroll
      for (int c4 = 0; c4 < 16; ++c4){
        float4 v = *(const float4*)&M[r*512 + k0 + c4*4];
        y[c4*4+0]=v.x; y[c4*4+1]=v.y; y[c4*4+2]=v.z; y[c4*4+3]=v.w;
      }
      #pragma unroll
      for (int c = 0; c < 64; ++c){
        const float yc = y[c] * dinv[c];
        y[c] = yc;
        const int ja0 = (c+1) & ~3;
        #pragma unroll
        for (int j = ja0; j < 64; j += 4){
          float4 f = *(const float4*)&fc[c*64 + j];   // wave-uniform; zeros at j<=c
          y[j+0] -= yc * f.x;
          y[j+1] -= yc * f.y;
          y[j+2] -= yc * f.z;
          y[j+3] -= yc * f.w;
        }
      }
      #pragma unroll
      for (int c4 = 0; c4 < 16; ++c4){
        float4 v;
        v.x=y[c4*4+0]; v.y=y[c4*4+1]; v.z=y[c4*4+2]; v.w=y[c4*4+3];
        *(float4*)&M[r*512 + k0 + c4*4] = v;
      }
    }
  } else {
    const int wid = threadIdx.x >> 6;
    const int b = mb_base + ((int)blockIdx.x - tb)*4 + wid;
    if (b < mb_end)
      small_role(align, mus, ws, b, ((float4*)smem) + wid*64, smem + 1024 + wid*64);
  }
}

// ---------------- syrk tiles (blocks < ntiles; tile 0 also chols next diag) + slice ----------------
__global__ __launch_bounds__(256) void k_syrkS(const int* __restrict__ align,
    const float* __restrict__ mus, float* ws, int k0, int ntiles, int mb_base, int mb_end){
  __shared__ float smem[12352];   // AT 4096 | BT 4096 | Tile 4096 | colbuf 64  (small role overlays [0,1280))
  if ((int)blockIdx.x < ntiles){
    float* AT   = smem;
    float* BT   = smem + 4096;
    float* Tile = smem + 8192;
    float* colbuf = smem + 12288;
    const int t = threadIdx.x;
    int tp = blockIdx.x;
    int a = 0;
    while ((a + 1) * (a + 2) / 2 <= tp) a++;
    const int bb = tp - a * (a + 1) / 2;
    const int Ra = k0 + 64 + a * 64;
    const int Cb = k0 + 64 + bb * 64;
    float* M = ws + WS_M;
    {
      const int row = t & 63;
      const int cb  = (t >> 6) * 16;
      #pragma unroll
      for (int q = 0; q < 4; ++q){
        const int c = cb + q*4;
        float4 v = *(const float4*)&M[(Ra + row)*512 + k0 + c];
        AT[(c+0)*64+row]=v.x; AT[(c+1)*64+row]=v.y; AT[(c+2)*64+row]=v.z; AT[(c+3)*64+row]=v.w;
        float4 w = *(const float4*)&M[(Cb + row)*512 + k0 + c];
        BT[(c+0)*64+row]=w.x; BT[(c+1)*64+row]=w.y; BT[(c+2)*64+row]=w.z; BT[(c+3)*64+row]=w.w;
      }
    }
    __syncthreads();
    const int ti = t >> 4, tj = t & 15;
    float acc[4][4];
    #pragma unroll
    for (int i = 0; i < 4; ++i)
      #pragma unroll
      for (int j = 0; j < 4; ++j) acc[i][j] = 0.f;
    #pragma unroll 8
    for (int k = 0; k < 64; ++k){
      float4 av = *(const float4*)&AT[k*64 + ti*4];
      float4 bv = *(const float4*)&BT[k*64 + tj*4];
      acc[0][0]+=av.x*bv.x; acc[0][1]+=av.x*bv.y; acc[0][2]+=av.x*bv.z; acc[0][3]+=av.x*bv.w;
      acc[1][0]+=av.y*bv.x; acc[1][1]+=av.y*bv.y; acc[1][2]+=av.y*bv.z; acc[1][3]+=av.y*bv.w;
      acc[2][0]+=av.z*bv.x; acc[2][1]+=av.z*bv.y; acc[2][2]+=av.z*bv.z; acc[2][3]+=av.z*bv.w;
      acc[3][0]+=av.w*bv.x; acc[3][1]+=av.w*bv.y; acc[3][2]+=av.w*bv.z; acc[3][3]+=av.w*bv.w;
    }
    const int fuse = (tp == 0);
    #pragma unroll
    for (int i = 0; i < 4; ++i){
      const int r = Ra + ti*4 + i;
      float4 v = *(float4*)&M[r*512 + Cb + tj*4];
      v.x -= acc[i][0]; v.y -= acc[i][1]; v.z -= acc[i][2]; v.w -= acc[i][3];
      *(float4*)&M[r*512 + Cb + tj*4] = v;
      if (fuse) *(float4*)&Tile[(ti*4+i)*64 + tj*4] = v;
    }
    if (fuse){                      // block-uniform: safe barrier
      __syncthreads();
      if (threadIdx.x < 64) chol64_wave(Tile, 64, ws, colbuf);   // next panel's factor
    }
  } else {
    const int wid = threadIdx.x >> 6;
    const int b = mb_base + ((int)blockIdx.x - ntiles)*4 + wid;
    if (b < mb_end)
      small_role(align, mus, ws, b, ((float4*)smem) + wid*64, smem + 1024 + wid*64);
  }
}

// ---------------- final ----------------
__global__ __launch_bounds__(512) void k_final(const float* __restrict__ ws, float* __restrict__ out){
  __shared__ float red[512];
  int t = threadIdx.x;
  float v = 0.f;
  if (t < 500){
    const float* s = ws + WS_S34 + t*32;
    float mx = -1e30f;
    for (int a = 0; a < 32; ++a) mx = fmaxf(mx, s[a]);
    float sum = 0.f;
    for (int a = 0; a < 32; ++a) sum += expf(s[a] - mx);
    v = mx + logf(sum);
  }
  red[t] = v;
  __syncthreads();
  for (int s = 256; s; s >>= 1){ if (t < s) red[t] += red[t+s]; __syncthreads(); }
  if (t == 0){
    float step1 = ws[WS_SCAL+0];
    float step2 = ws[WS_SCAL+1];
    float ld    = ws[WS_SCAL+2];
    float step34 = red[0] - 500.f*ld;
    out[0] = -(step1 + step2 + step34);
  }
}

extern "C" void kernel_launch(void* const* d_in, const int* in_sizes, int n_in,
                              void* d_out, int out_size, void* d_ws, size_t ws_size,
                              hipStream_t stream) {
  const float* colors = (const float*)d_in[0];
  const int*   align  = (const int*)  d_in[1];
  const float* mus    = (const float*)d_in[2];
  const float* fkw1   = (const float*)d_in[3];
  const float* fkb1   = (const float*)d_in[4];
  const float* fkw2   = (const float*)d_in[5];
  const float* fkb2   = (const float*)d_in[6];
  const float* dfw1   = (const float*)d_in[7];
  const float* dfb1   = (const float*)d_in[8];
  const float* dfw2   = (const float*)d_in[9];
  const float* dfb2   = (const float*)d_in[10];
  float* ws  = (float*)d_ws;
  float* out = (float*)d_out;

  const int NM = 16000;
  const int NSLICE = 15;
  const int mper = (NM + NSLICE - 1) / NSLICE;   // 1067
  int s = 0;

  hipLaunchKernelGGL(k_prep, dim3(1), dim3(512), 0, stream,
                     mus, fkw1, fkb1, fkw2, fkb2, dfw1, dfw2, ws);
  hipLaunchKernelGGL(k_mid,  dim3(1149), dim3(256), 0, stream, colors, dfb1, dfb2, mus, ws);

  {  // panel-0 diag chol + slice
    int base = s*mper, cnt = (base + mper <= NM) ? mper : (NM - base); s++;
    hipLaunchKernelGGL(k_d0s, dim3(1 + (cnt+3)/4), dim3(256), 0, stream,
                       align, mus, ws, base, base + cnt);
  }
  for (int p = 0; p < 7; ++p){
    const int k0 = p * 64;
    const int rows = 448 - k0;
    const int tb = (rows + 255) / 256;
    {
      int base = s*mper, cnt = (base + mper <= NM) ? mper : (NM - base); s++;
      hipLaunchKernelGGL(k_trsmS, dim3(tb + (cnt+3)/4), dim3(256), 0, stream,
                         align, mus, ws, k0, tb, base, base + cnt);
    }
    const int m = 7 - p;
    const int nt = m*(m+1)/2;
    {
      int base = s*mper, cnt = (base + mper <= NM) ? mper : (NM - base); s++;
      hipLaunchKernelGGL(k_syrkS, dim3(nt + (cnt+3)/4), dim3(256), 0, stream,
                         align, mus, ws, k0, nt, base, base + cnt);
    }
  }
  hipLaunchKernelGGL(k_final, dim3(1), dim3(512), 0, stream, ws, out);
}

// Round 6
// 899.952 us; speedup vs baseline: 1.4052x; 1.0721x over previous
//
#include <hip/hip_runtime.h>
#include <math.h>

#define LOG2PI_F 1.8378770664093453f

// ws layout (floats)
#define WS_Q    0                       // 512
#define WS_SCAL 512                     // [0]=step1 [1]=step2 [2]=logdet_LI [3..11]=w1_inv [12..20]=w2_inv
#define WS_M    544                     // 512*512
#define WS_CHR  (544 + 512*512)         // 500*64*3
#define WS_S34  (WS_CHR + 96000)        // 16000
#define WS_FC   (WS_S34 + 16000)        // 4096: current panel factor, col-major zero-padded
#define WS_DINV (WS_FC + 4096)          // 64: 1/Lcc

__device__ inline void inv3(const float* w, float* out){
  float a=w[0],b=w[1],c=w[2],d=w[3],e=w[4],f=w[5],g=w[6],h=w[7],i=w[8];
  float A = e*i - f*h;
  float B = -(d*i - f*g);
  float C = d*h - e*g;
  float det = a*A + b*B + c*C;
  float id = 1.0f/det;
  out[0]=A*id;            out[1]=-(b*i - c*h)*id; out[2]=(b*f - c*e)*id;
  out[3]=B*id;            out[4]=(a*i - c*g)*id;  out[5]=-(a*f - c*d)*id;
  out[6]=C*id;            out[7]=-(a*h - b*g)*id; out[8]=(a*e - b*d)*id;
}

// ---------------- prep ----------------
__global__ __launch_bounds__(512) void k_prep(const float* __restrict__ mus,
    const float* __restrict__ fkw1, const float* __restrict__ fkb1,
    const float* __restrict__ fkw2, const float* __restrict__ fkb2,
    const float* __restrict__ dfw1, const float* __restrict__ dfw2,
    float* ws){
  int t = threadIdx.x;
  __shared__ float red[512];
  float m0 = mus[t*3+0], m1 = mus[t*3+1], m2 = mus[t*3+2];
  float h0 = tanhf(fkw1[0]*m0 + fkw1[1]*m1 + fkw1[2]*m2 + fkb1[0]);
  float h1 = tanhf(fkw1[3]*m0 + fkw1[4]*m1 + fkw1[5]*m2 + fkb1[1]);
  float h2 = tanhf(fkw1[6]*m0 + fkw1[7]*m1 + fkw1[8]*m2 + fkb1[2]);
  float logq = fkw2[0]*h0 + fkw2[1]*h1 + fkw2[2]*h2 + fkb2[0];
  ws[WS_Q + t] = expf(logq);
  red[t] = -0.5f*(m0*m0 + m1*m1 + m2*m2);
  __syncthreads();
  for (int s = 256; s; s >>= 1){ if (t < s) red[t] += red[t+s]; __syncthreads(); }
  if (t == 0){
    ws[WS_SCAL+1] = red[0] - 512.0f*1.5f*LOG2PI_F;
    ws[WS_SCAL+0] = 512.0f*logf(500.0f) - 500.0f - lgammaf(513.0f);
    ws[WS_SCAL+2] = 0.0f;
    inv3(dfw1, ws + WS_SCAL + 3);
    inv3(dfw2, ws + WS_SCAL + 12);
  }
}

// ---------------- fused: chromes (blocks 0..124) + build L+I (blocks 125..1148) ----------------
__global__ __launch_bounds__(256) void k_mid(const float* __restrict__ colors,
    const float* __restrict__ dfb1, const float* __restrict__ dfb2,
    const float* __restrict__ mus, float* ws){
  if (blockIdx.x < 125){
    int id = blockIdx.x*256 + threadIdx.x;          // < 32000
    const float* w1i = ws + WS_SCAL + 3;
    const float* w2i = ws + WS_SCAL + 12;
    float c0 = colors[id*3+0] - dfb2[0];
    float c1 = colors[id*3+1] - dfb2[1];
    float c2 = colors[id*3+2] - dfb2[2];
    float z0 = w2i[0]*c0 + w2i[1]*c1 + w2i[2]*c2;
    float z1 = w2i[3]*c0 + w2i[4]*c1 + w2i[5]*c2;
    float z2 = w2i[6]*c0 + w2i[7]*c1 + w2i[8]*c2;
    const float lo = -1.0f + 1e-6f, hi = 1.0f - 1e-6f;
    z0 = atanhf(fminf(fmaxf(z0, lo), hi)) - dfb1[0];
    z1 = atanhf(fminf(fmaxf(z1, lo), hi)) - dfb1[1];
    z2 = atanhf(fminf(fmaxf(z2, lo), hi)) - dfb1[2];
    ws[WS_CHR + id*3+0] = w1i[0]*z0 + w1i[1]*z1 + w1i[2]*z2;
    ws[WS_CHR + id*3+1] = w1i[3]*z0 + w1i[4]*z1 + w1i[5]*z2;
    ws[WS_CHR + id*3+2] = w1i[6]*z0 + w1i[7]*z1 + w1i[8]*z2;
  } else {
    int id = (blockIdx.x - 125)*256 + threadIdx.x;  // < 262144
    int i = id >> 9, j = id & 511;
    float dx = mus[i*3+0]-mus[j*3+0];
    float dy = mus[i*3+1]-mus[j*3+1];
    float dz = mus[i*3+2]-mus[j*3+2];
    float d2 = dx*dx + dy*dy + dz*dz;
    float v = ws[WS_Q+i]*ws[WS_Q+j]*expf(-0.5f*d2);
    if (i == j) v += 1.0f;
    ws[WS_M + id] = v;
  }
}

// ---------------- 64x64 chol by one wave; factor -> ws (zero-padded col-major) ----------------
__device__ __forceinline__ void chol64_wave(const float* src, int stride, float* ws, float* colbuf){
  const int t = threadIdx.x & 63;
  float x[64];
  #pragma unroll
  for (int c4 = 0; c4 < 16; ++c4){
    float4 v = *(const float4*)&src[t*stride + c4*4];
    x[c4*4+0]=v.x; x[c4*4+1]=v.y; x[c4*4+2]=v.z; x[c4*4+3]=v.w;
  }
  float mydiag = 1.f;
  #pragma unroll
  for (int c = 0; c < 64; ++c){
    float piv = fmaxf(__shfl(x[c], c), 1e-30f);
    float rs = rsqrtf(piv);
    float xc = x[c] * rs;                       // lane c: sqrt(piv)
    if (t == c) mydiag = xc;
    float cval = (t > c) ? xc : 0.f;
    colbuf[t] = cval;                           // same-wave LDS ordering
    x[c] = xc;
    ws[WS_FC + c*64 + t] = cval;                // factor column to global
    if (t == c) ws[WS_DINV + c] = rs;
    const int ja0 = (c+1) & ~3;
    #pragma unroll
    for (int j = ja0; j < 64; j += 4){
      float4 f = *(const float4*)&colbuf[j];    // zeros kill j<=c
      x[j+0] -= xc * f.x;
      x[j+1] -= xc * f.y;
      x[j+2] -= xc * f.z;
      x[j+3] -= xc * f.w;
    }
  }
  float lg = __logf(mydiag);
  #pragma unroll
  for (int off = 32; off; off >>= 1) lg += __shfl_down(lg, off);
  if (t == 0) atomicAdd(&ws[WS_SCAL + 2], 2.f * lg);
}

// ---------------- chain: diag chol of panel 0 ----------------
__global__ __launch_bounds__(64) void k_d0(float* ws){
  __shared__ float colbuf[64];
  chol64_wave(ws + WS_M, 512, ws, colbuf);
}

// ---------------- chain: trsm, rows k0+64..511, one per thread ----------------
__global__ __launch_bounds__(256) void k_trsm(float* ws, int k0){
  const int rel = (int)blockIdx.x*256 + threadIdx.x;
  const int rows = 448 - k0;
  if (rel >= rows) return;
  const int r = k0 + 64 + rel;
  float* M = ws + WS_M;
  const float* fc   = ws + WS_FC;
  const float* dinv = ws + WS_DINV;
  float y[64];
  #pragma unroll
  for (int c4 = 0; c4 < 16; ++c4){
    float4 v = *(const float4*)&M[r*512 + k0 + c4*4];
    y[c4*4+0]=v.x; y[c4*4+1]=v.y; y[c4*4+2]=v.z; y[c4*4+3]=v.w;
  }
  #pragma unroll
  for (int c = 0; c < 64; ++c){
    const float yc = y[c] * dinv[c];
    y[c] = yc;
    const int ja0 = (c+1) & ~3;
    #pragma unroll
    for (int j = ja0; j < 64; j += 4){
      float4 f = *(const float4*)&fc[c*64 + j];   // wave-uniform; zeros at j<=c
      y[j+0] -= yc * f.x;
      y[j+1] -= yc * f.y;
      y[j+2] -= yc * f.z;
      y[j+3] -= yc * f.w;
    }
  }
  #pragma unroll
  for (int c4 = 0; c4 < 16; ++c4){
    float4 v;
    v.x=y[c4*4+0]; v.y=y[c4*4+1]; v.z=y[c4*4+2]; v.w=y[c4*4+3];
    *(float4*)&M[r*512 + k0 + c4*4] = v;
  }
}

// ---------------- chain: syrk tiles; tile 0 also chols the next diag block ----------------
__global__ __launch_bounds__(256) void k_syrk(float* ws, int k0){
  __shared__ float smem[12352];   // AT 4096 | BT 4096 | Tile 4096 | colbuf 64
  float* AT   = smem;
  float* BT   = smem + 4096;
  float* Tile = smem + 8192;
  float* colbuf = smem + 12288;
  const int t = threadIdx.x;
  int tp = blockIdx.x;
  int a = 0;
  while ((a + 1) * (a + 2) / 2 <= tp) a++;
  const int bb = tp - a * (a + 1) / 2;
  const int Ra = k0 + 64 + a * 64;
  const int Cb = k0 + 64 + bb * 64;
  float* M = ws + WS_M;
  {
    const int row = t & 63;
    const int cb  = (t >> 6) * 16;
    #pragma unroll
    for (int q = 0; q < 4; ++q){
      const int c = cb + q*4;
      float4 v = *(const float4*)&M[(Ra + row)*512 + k0 + c];
      AT[(c+0)*64+row]=v.x; AT[(c+1)*64+row]=v.y; AT[(c+2)*64+row]=v.z; AT[(c+3)*64+row]=v.w;
      float4 w = *(const float4*)&M[(Cb + row)*512 + k0 + c];
      BT[(c+0)*64+row]=w.x; BT[(c+1)*64+row]=w.y; BT[(c+2)*64+row]=w.z; BT[(c+3)*64+row]=w.w;
    }
  }
  __syncthreads();
  const int ti = t >> 4, tj = t & 15;
  float acc[4][4];
  #pragma unroll
  for (int i = 0; i < 4; ++i)
    #pragma unroll
    for (int j = 0; j < 4; ++j) acc[i][j] = 0.f;
  #pragma unroll 8
  for (int k = 0; k < 64; ++k){
    float4 av = *(const float4*)&AT[k*64 + ti*4];
    float4 bv = *(const float4*)&BT[k*64 + tj*4];
    acc[0][0]+=av.x*bv.x; acc[0][1]+=av.x*bv.y; acc[0][2]+=av.x*bv.z; acc[0][3]+=av.x*bv.w;
    acc[1][0]+=av.y*bv.x; acc[1][1]+=av.y*bv.y; acc[1][2]+=av.y*bv.z; acc[1][3]+=av.y*bv.w;
    acc[2][0]+=av.z*bv.x; acc[2][1]+=av.z*bv.y; acc[2][2]+=av.z*bv.z; acc[2][3]+=av.z*bv.w;
    acc[3][0]+=av.w*bv.x; acc[3][1]+=av.w*bv.y; acc[3][2]+=av.w*bv.z; acc[3][3]+=av.w*bv.w;
  }
  const int fuse = (tp == 0);
  #pragma unroll
  for (int i = 0; i < 4; ++i){
    const int r = Ra + ti*4 + i;
    float4 v = *(float4*)&M[r*512 + Cb + tj*4];
    v.x -= acc[i][0]; v.y -= acc[i][1]; v.z -= acc[i][2]; v.w -= acc[i][3];
    *(float4*)&M[r*512 + Cb + tj*4] = v;
    if (fuse) *(float4*)&Tile[(ti*4+i)*64 + tj*4] = v;
  }
  if (fuse){                      // block-uniform branch: barrier is safe
    __syncthreads();
    if (threadIdx.x < 64) chol64_wave(Tile, 64, ws, colbuf);   // next panel's factor
  }
}

// ---------------- 16000 small 64x64 logdets + step4 (R4 known-good) ----------------
__global__ __launch_bounds__(256) void k_small(const int* __restrict__ align,
    const float* __restrict__ mus, float* ws){
  const int wid = threadIdx.x >> 6;
  const int b = blockIdx.x*4 + wid;      // matrix id = l*32+a, < 16000
  const int t = threadIdx.x & 63;
  __shared__ float4 pt[4][64];
  __shared__ float col[4][64];
  const int idx = align[b*64 + t];
  float4 own;
  own.x = mus[idx*3+0]; own.y = mus[idx*3+1]; own.z = mus[idx*3+2];
  own.w = ws[WS_Q + idx];
  pt[wid][t] = own;
  float x[64];
  #pragma unroll
  for (int j = 0; j < 64; ++j){
    float4 o = pt[wid][j];                 // uniform b128 broadcast
    float dx = own.x - o.x, dy = own.y - o.y, dz = own.z - o.z;
    float v = own.w * o.w * __expf(-0.5f*(dx*dx + dy*dy + dz*dz));
    x[j] = (j == t) ? v + 1e-6f : v;
  }
  float mydiag = 1.f;
  #pragma unroll
  for (int c = 0; c < 64; ++c){
    float piv = fmaxf(__shfl(x[c], c), 1e-30f);
    float rs = rsqrtf(piv);
    float xc = x[c] * rs;
    if (t == c) mydiag = xc;
    col[wid][t] = (t > c) ? xc : 0.f;
    const int ja0 = (c+1) & ~3;
    #pragma unroll
    for (int j = ja0; j < 64; j += 4){
      float4 cv = *(const float4*)&col[wid][j];
      x[j+0] -= xc * cv.x;
      x[j+1] -= xc * cv.y;
      x[j+2] -= xc * cv.z;
      x[j+3] -= xc * cv.w;
    }
  }
  const float* ch = ws + WS_CHR + ((b >> 5)*64 + t)*3;
  float d0 = ch[0] - own.x, d1 = ch[1] - own.y, d2 = ch[2] - own.z;
  float v = 2.f*__logf(mydiag) - 0.5f*(d0*d0 + d1*d1 + d2*d2);
  #pragma unroll
  for (int off = 32; off; off >>= 1) v += __shfl_down(v, off);
  if (t == 0) ws[WS_S34 + b] = v - 96.f*LOG2PI_F;
}

// ---------------- final ----------------
__global__ __launch_bounds__(512) void k_final(const float* __restrict__ ws, float* __restrict__ out){
  __shared__ float red[512];
  int t = threadIdx.x;
  float v = 0.f;
  if (t < 500){
    const float* s = ws + WS_S34 + t*32;
    float mx = -1e30f;
    for (int a = 0; a < 32; ++a) mx = fmaxf(mx, s[a]);
    float sum = 0.f;
    for (int a = 0; a < 32; ++a) sum += expf(s[a] - mx);
    v = mx + logf(sum);
  }
  red[t] = v;
  __syncthreads();
  for (int s = 256; s; s >>= 1){ if (t < s) red[t] += red[t+s]; __syncthreads(); }
  if (t == 0){
    float step1 = ws[WS_SCAL+0];
    float step2 = ws[WS_SCAL+1];
    float ld    = ws[WS_SCAL+2];
    float step34 = red[0] - 500.f*ld;
    out[0] = -(step1 + step2 + step34);
  }
}

extern "C" void kernel_launch(void* const* d_in, const int* in_sizes, int n_in,
                              void* d_out, int out_size, void* d_ws, size_t ws_size,
                              hipStream_t stream) {
  const float* colors = (const float*)d_in[0];
  const int*   align  = (const int*)  d_in[1];
  const float* mus    = (const float*)d_in[2];
  const float* fkw1   = (const float*)d_in[3];
  const float* fkb1   = (const float*)d_in[4];
  const float* fkw2   = (const float*)d_in[5];
  const float* fkb2   = (const float*)d_in[6];
  const float* dfw1   = (const float*)d_in[7];
  const float* dfb1   = (const float*)d_in[8];
  const float* dfw2   = (const float*)d_in[9];
  const float* dfb2   = (const float*)d_in[10];
  float* ws  = (float*)d_ws;
  float* out = (float*)d_out;

  hipLaunchKernelGGL(k_prep, dim3(1), dim3(512), 0, stream,
                     mus, fkw1, fkb1, fkw2, fkb2, dfw1, dfw2, ws);
  hipLaunchKernelGGL(k_mid,  dim3(1149), dim3(256), 0, stream, colors, dfb1, dfb2, mus, ws);

  hipLaunchKernelGGL(k_d0, dim3(1), dim3(64), 0, stream, ws);
  for (int p = 0; p < 7; ++p){
    const int k0 = p * 64;
    const int rows = 448 - k0;
    const int tb = (rows + 255) / 256;
    hipLaunchKernelGGL(k_trsm, dim3(tb), dim3(256), 0, stream, ws, k0);
    const int m = 7 - p;
    hipLaunchKernelGGL(k_syrk, dim3(m*(m+1)/2), dim3(256), 0, stream, ws, k0);
  }
  hipLaunchKernelGGL(k_small, dim3(4000), dim3(256), 0, stream, align, mus, ws);
  hipLaunchKernelGGL(k_final, dim3(1), dim3(512), 0, stream, ws, out);
}